// Round 1
// baseline (591.815 us; speedup 1.0000x reference)
//
#include <hip/hip_runtime.h>
#include <math.h>

// Problem constants (from reference setup_inputs): B=4,H=16,S=8192,D=128
#define BH   64      // B*H
#define SEQ  8192
#define DIM  128
#define NB   16      // num_blocks = S / BLOCK_SIZE
#define BS   512     // BLOCK_SIZE

// ---------------------------------------------------------------------------
// Kernel 1: kmean_d[bh][nb][d] = mean over BS rows of k, double accumulation,
// stored as DOUBLE (removes per-FMA v_cvt_f64_f32 on the k operand in K2).
// Also fused: query_block_indices[s] = s >> 9 (grid covers SEQ easily).
// Grid: BH*NB = 1024 blocks, 256 threads. Coalesced float4 reads.
// ---------------------------------------------------------------------------
__global__ __launch_bounds__(256) void kmean_kernel(const float* __restrict__ k,
                                                    double* __restrict__ kmean_d,
                                                    int* __restrict__ qbi) {
  int gt = blockIdx.x * 256 + threadIdx.x;
  if (gt < SEQ) qbi[gt] = gt >> 9;

  int blk = blockIdx.x;            // 0..BH*NB-1
  int bh  = blk >> 4;
  int nb  = blk & 15;
  const float4* base = (const float4*)(k + ((size_t)bh * SEQ + (size_t)nb * BS) * DIM);
  int t  = threadIdx.x;
  int c4 = t & 31;                 // float4 column within row
  int r0 = t >> 5;                 // 0..7
  double a0 = 0, a1 = 0, a2 = 0, a3 = 0;
  for (int r = r0; r < BS; r += 8) {
    float4 v = base[r * 32 + c4];
    a0 += (double)v.x; a1 += (double)v.y; a2 += (double)v.z; a3 += (double)v.w;
  }
  __shared__ double red[8][32][4];
  red[r0][c4][0] = a0; red[r0][c4][1] = a1;
  red[r0][c4][2] = a2; red[r0][c4][3] = a3;
  __syncthreads();
  if (r0 == 0) {
    double s0 = 0, s1 = 0, s2 = 0, s3 = 0;
#pragma unroll
    for (int r = 0; r < 8; ++r) {
      s0 += red[r][c4][0]; s1 += red[r][c4][1];
      s2 += red[r][c4][2]; s3 += red[r][c4][3];
    }
    const double inv = 1.0 / (double)BS;    // exact power of two
    double2* dst = (double2*)kmean_d + ((size_t)(bh * NB + nb) * 32 + c4) * 2;
    double2 o0, o1;
    o0.x = s0 * inv; o0.y = s1 * inv;
    o1.x = s2 * inv; o1.y = s3 * inv;
    dst[0] = o0; dst[1] = o1;
  }
}

// ---------------------------------------------------------------------------
// Kernel 2: thread-per-query scores + causal mask + stable top-4.
//
// Restructure vs previous version: each thread owns ONE query end-to-end.
//  - q staged per-wave through a small XOR-swizzled LDS transpose buffer:
//    coalesced global reads (64B segments), conflict-free b128 LDS writes
//    AND conflict-free per-thread row reads (col' = col ^ (row&3) makes both
//    sides hit the 8-words/bank LDS minimum).
//  - kmean staged in LDS as double2 (broadcast reads, no cvt in inner loop).
//  - ZERO shuffles (previous version: ~400 fp64 ds_bpermute pairs/wave).
//  - top-4 computed ONCE per query (previous: 8x redundant across sub-lanes)
//    on packed sortable u64 keys: orderbits(score) with low 4 bits = 15-n
//    reproduces jax.lax.top_k stable descending order exactly (ties -> lower
//    index wins; masked blocks all share the -inf key and order by index).
//  - causal skip branch hoisted to SALU via readfirstlane (qb is wave-uniform:
//    64 consecutive queries always lie inside one 512-query block).
//
// Grid: BH*SEQ/256 = 2048 blocks x 256 thr (4 waves x 64 queries).
// LDS: 16 KB kmean + 4x4 KB q staging = 32 KB -> 4+ blocks/CU.
// ---------------------------------------------------------------------------
__global__ __launch_bounds__(256) void score_topk_kernel(const float* __restrict__ q,
                                                         const double* __restrict__ kmean_d,
                                                         int* __restrict__ out) {
  __shared__ double2 kkd[NB * 64];      // 16 rows x 128 doubles = 16 KB
  __shared__ float4  qs[4][256];        // per-wave 64 rows x 4 float4 = 4 KB

  int t      = threadIdx.x;
  int qstart = blockIdx.x * 256;        // first global query of this block
  int bh     = qstart >> 13;

  const double2* ksrc = (const double2*)kmean_d + (size_t)bh * NB * 64;
#pragma unroll
  for (int i = 0; i < 4; ++i) kkd[i * 256 + t] = ksrc[i * 256 + t];
  __syncthreads();

  int wave = t >> 6;
  int lane = t & 63;
  int qw   = qstart + wave * 64;        // wave's first query
  int qb   = (qw & (SEQ - 1)) >> 9;     // query block; uniform across the wave
  int qbs  = __builtin_amdgcn_readfirstlane(qb);

  int fc = lane & 3;                    // load column (float4) within chunk
  int rr = lane >> 2;                   // 0..15 (row group)

  const float4* qbase = (const float4*)(q + (size_t)qw * DIM);
  float4* myqs = qs[wave];              // wave-private: no __syncthreads needed

  double ps[NB];
#pragma unroll
  for (int n = 0; n < NB; ++n) ps[n] = 0.0;

  // prologue: load chunk 0 (16 floats of each of the wave's 64 rows)
  float4 ld[4];
#pragma unroll
  for (int i = 0; i < 4; ++i)
    ld[i] = qbase[(size_t)(i * 16 + rr) * 32 + fc];

  for (int c = 0; c < 8; ++c) {
    // stage chunk c into wave-private LDS, swizzled: [row][col ^ (row&3)]
#pragma unroll
    for (int i = 0; i < 4; ++i)
      myqs[(i * 16 + rr) * 4 + (fc ^ (rr & 3))] = ld[i];
    __builtin_amdgcn_wave_barrier();    // keep write->read order (same wave)

    // read own row (conflict-free) and widen once per chunk
    double qd[16];
#pragma unroll
    for (int j = 0; j < 4; ++j) {
      float4 v = myqs[lane * 4 + (j ^ (lane & 3))];
      qd[4 * j + 0] = (double)v.x; qd[4 * j + 1] = (double)v.y;
      qd[4 * j + 2] = (double)v.z; qd[4 * j + 3] = (double)v.w;
    }

    // issue next chunk's global loads under the FMA phase (depth-1 pipeline)
    if (c < 7) {
#pragma unroll
      for (int i = 0; i < 4; ++i)
        ld[i] = qbase[(size_t)(i * 16 + rr) * 32 + (c + 1) * 4 + fc];
    }

    // accumulate: pure v_fma_f64 with LDS-broadcast k operand
#pragma unroll
    for (int n = 0; n < NB; ++n) {
      if (n <= qbs) {                   // SALU branch (qbs wave-uniform SGPR)
        const double2* kr = &kkd[n * 64 + c * 8];
        double a = ps[n];
#pragma unroll
        for (int j2 = 0; j2 < 8; ++j2) {
          double2 kv = kr[j2];
          a = fma(qd[2 * j2],     kv.x, a);
          a = fma(qd[2 * j2 + 1], kv.y, a);
        }
        ps[n] = a;
      }
    }
  }

  // ---- stable top-4 on packed sortable keys (per-thread, once) ----
  // orderbits: monotonic double->u64 map; low 4 bits replaced by (15-n) so
  // exact ties (incl. the shared -inf of masked blocks) break to lower n,
  // matching jax.lax.top_k's stable ordering.
  unsigned long long keys[NB];
#pragma unroll
  for (int n = 0; n < NB; ++n) {
    double v = (n <= qbs) ? ps[n] : -INFINITY;
    long long u = __double_as_longlong(v);
    unsigned long long sk =
        (unsigned long long)(u ^ ((u >> 63) | 0x8000000000000000LL));
    keys[n] = (sk & ~0xFULL) | (unsigned long long)(15 - n);
  }
  int res[4];
#pragma unroll
  for (int pp = 0; pp < 4; ++pp) {
    unsigned long long best = keys[0];
#pragma unroll
    for (int n = 1; n < NB; ++n) best = (keys[n] > best) ? keys[n] : best;
    res[pp] = 15 - (int)(best & 0xFULL);
#pragma unroll
    for (int n = 0; n < NB; ++n) keys[n] = (keys[n] == best) ? 0ULL : keys[n];
  }

  int myq = qw + lane;
  *(int4*)(out + (size_t)myq * 4) = make_int4(res[0], res[1], res[2], res[3]);
}

extern "C" void kernel_launch(void* const* d_in, const int* in_sizes, int n_in,
                              void* d_out, int out_size, void* d_ws, size_t ws_size,
                              hipStream_t stream) {
  (void)in_sizes; (void)n_in; (void)out_size; (void)ws_size;
  const float* q = (const float*)d_in[0];
  const float* k = (const float*)d_in[1];
  double* kmean_d = (double*)d_ws;             // BH*NB*DIM doubles = 1 MB
  int*    out     = (int*)d_out;
  int*    qbi     = out + (size_t)BH * SEQ * 4;

  hipLaunchKernelGGL(kmean_kernel, dim3(BH * NB), dim3(256), 0, stream,
                     k, kmean_d, qbi);
  hipLaunchKernelGGL(score_topk_kernel, dim3(BH * SEQ / 256), dim3(256), 0, stream,
                     q, kmean_d, out);
}